// Round 3
// baseline (147.975 us; speedup 1.0000x reference)
//
#include <hip/hip_runtime.h>

// image (1,1024,1024) f32, x (16,1,1024,1024) f32, W_KL (9,1,3,3) f32, b_KL (9,) f32.
// y[b,h,w] = sum_{a,d} (conv(image,W_KL)[a*3+d][h,w] + b[a*3+d]) * x[b,h+a-1,w+d-1]
#define IH 1024
#define IW 1024
#define NB 16
#define BPB 4  // batches per block (gridDim.z = NB/BPB)

typedef float v4f __attribute__((ext_vector_type(4)));  // native vector: NT-store ok

// Load row[w0-1 .. w0+4] into o[0..5] with zero-pad.
// One float4 per lane; left/right neighbors come from adjacent lanes via shfl.
// `valid` (row in range) is wave-uniform: wave = one ty row of the 64x8 block.
__device__ __forceinline__ void load_row6(const float* __restrict__ row, int w0,
                                          int tx, bool valid, float o[6]) {
    if (valid) {
        const v4f m = *(const v4f*)(row + w0);
        float left  = __shfl_up(m.w, 1);   // lane i gets lane i-1's m.w
        float right = __shfl_down(m.x, 1); // lane i gets lane i+1's m.x
        if (tx == 0)  left  = (w0 > 0)      ? row[w0 - 1] : 0.f;
        if (tx == 63) right = (w0 + 4 < IW) ? row[w0 + 4] : 0.f;
        o[0] = left; o[1] = m.x; o[2] = m.y; o[3] = m.z; o[4] = m.w; o[5] = right;
    } else {
#pragma unroll
        for (int j = 0; j < 6; ++j) o[j] = 0.f;
    }
}

// Block: 64 x 8 threads -> tile 256 wide x 8 tall, BPB batches.
// Grid: (1024/256, 1024/8, 16/BPB) = (4, 128, 4) = 2048 blocks.
__global__ __launch_bounds__(512) void fused_smblock(
    const float* __restrict__ image,
    const float* __restrict__ x,
    const float* __restrict__ Wk,
    const float* __restrict__ bk,
    float* __restrict__ out)
{
    const int tx = threadIdx.x;               // 0..63 (one wave per row)
    const int ty = threadIdx.y;               // 0..7
    const int w0 = blockIdx.x * 256 + tx * 4; // float4-aligned
    const int h  = blockIdx.y * 8 + ty;

    // conv weights / bias (uniform addresses -> scalar loads)
    float wk[81];
#pragma unroll
    for (int i = 0; i < 81; ++i) wk[i] = Wk[i];
    float bb[9];
#pragma unroll
    for (int c = 0; c < 9; ++c) bb[c] = bk[c];

    // image patch rows p[a][0..5]
    float p[3][6];
#pragma unroll
    for (int a = 0; a < 3; ++a) {
        const int hh = h + a - 1;
        load_row6(image + (size_t)(hh < 0 ? 0 : hh) * IW, w0, tx,
                  (hh >= 0 && hh < IH), p[a]);
    }

    // per-pixel kernels Kv[j][c], c = a*3+d (correlation, no flip)
    float Kv[4][9];
#pragma unroll
    for (int j = 0; j < 4; ++j) {
#pragma unroll
        for (int c = 0; c < 9; ++c) {
            float acc = bb[c];
#pragma unroll
            for (int i = 0; i < 3; ++i)
#pragma unroll
                for (int jj = 0; jj < 3; ++jj)
                    acc = fmaf(wk[c * 9 + i * 3 + jj], p[i][j + jj], acc);
            Kv[j][c] = acc;
        }
    }

    // apply to BPB batch planes
    const size_t plane = (size_t)IH * IW;
    const int b0 = blockIdx.z * BPB;
#pragma unroll 2
    for (int bi = 0; bi < BPB; ++bi) {
        const float* xp = x + (size_t)(b0 + bi) * plane;
        float r[3][6];
#pragma unroll
        for (int a = 0; a < 3; ++a) {
            const int hh = h + a - 1;
            load_row6(xp + (size_t)(hh < 0 ? 0 : hh) * IW, w0, tx,
                      (hh >= 0 && hh < IH), r[a]);
        }
        float yv[4];
#pragma unroll
        for (int j = 0; j < 4; ++j) {
            float acc = 0.f;
#pragma unroll
            for (int a = 0; a < 3; ++a)
#pragma unroll
                for (int d = 0; d < 3; ++d)
                    acc = fmaf(Kv[j][a * 3 + d], r[a][j + d], acc);
            yv[j] = acc;
        }
        // streaming store: don't pollute L2 (keeps x halo rows resident)
        v4f yvec; yvec.x = yv[0]; yvec.y = yv[1]; yvec.z = yv[2]; yvec.w = yv[3];
        __builtin_nontemporal_store(
            yvec, (v4f*)(out + (size_t)(b0 + bi) * plane + (size_t)h * IW + w0));
    }
}

extern "C" void kernel_launch(void* const* d_in, const int* in_sizes, int n_in,
                              void* d_out, int out_size, void* d_ws, size_t ws_size,
                              hipStream_t stream) {
    const float* image = (const float*)d_in[0]; // 1*1024*1024
    const float* x     = (const float*)d_in[1]; // 16*1*1024*1024
    const float* Wk    = (const float*)d_in[2]; // 9*1*3*3
    const float* bk    = (const float*)d_in[3]; // 9
    float* out = (float*)d_out;                 // 16*1024*1024 f32

    dim3 block(64, 8);
    dim3 grid(IW / 256, IH / 8, NB / BPB); // (4, 128, 4)
    fused_smblock<<<grid, block, 0, stream>>>(image, x, Wk, bk, out);
}